// Round 3
// baseline (46.347 us; speedup 1.0000x reference)
//
#include <hip/hip_runtime.h>
#include <stdint.h>

// ---------------------------------------------------------------------------
// JAX threefry2x32, PARTITIONABLE mode (jax_threefry_partitionable=True):
//   split(key,n)[i]              = threefry2x32(key, (0, i))          (both words)
//   random_bits(key,32,shape)[i] = fold: bits1 ^ bits2 of that block  (XOR!)
// (jax/_src/prng.py::_threefry_random_bits_partitionable: bit_width in
//  [8,16,32] -> convert(bits1 ^ bits2); only the 64-bit path keeps words.)
// ---------------------------------------------------------------------------

struct U2 { uint32_t x, y; };

__device__ __forceinline__ uint32_t rotl32(uint32_t v, int r) {
    return (v << r) | (v >> (32 - r));
}

__device__ U2 threefry2x32(uint32_t k0, uint32_t k1, uint32_t c0, uint32_t c1) {
    uint32_t ks2 = k0 ^ k1 ^ 0x1BD11BDAu;
    uint32_t x0 = c0 + k0;
    uint32_t x1 = c1 + k1;
#define TF_RND(r) { x0 += x1; x1 = rotl32(x1, r); x1 ^= x0; }
    TF_RND(13) TF_RND(15) TF_RND(26) TF_RND(6)
    x0 += k1;  x1 += ks2 + 1u;
    TF_RND(17) TF_RND(29) TF_RND(16) TF_RND(24)
    x0 += ks2; x1 += k0 + 2u;
    TF_RND(13) TF_RND(15) TF_RND(26) TF_RND(6)
    x0 += k0;  x1 += k1 + 3u;
    TF_RND(17) TF_RND(29) TF_RND(16) TF_RND(24)
    x0 += k1;  x1 += ks2 + 4u;
    TF_RND(13) TF_RND(15) TF_RND(26) TF_RND(6)
    x0 += ks2; x1 += k0 + 5u;
#undef TF_RND
    U2 r; r.x = x0; r.y = x1; return r;
}

// one 64-bit counter block: threefry2x32(key, (hi=0, lo=i))
__device__ __forceinline__ U2 blk(U2 key, uint32_t i) {
    return threefry2x32(key.x, key.y, 0u, i);
}
// partitionable random_bits(key, 32, ...)[i] = XOR-fold of the block
__device__ __forceinline__ uint32_t rb32(U2 key, uint32_t i) {
    U2 b = blk(key, i);
    return b.x ^ b.y;
}

// jax uniform [0,1): bitcast((bits>>9)|0x3f800000) - 1.0
__device__ __forceinline__ float u01(uint32_t bits) {
    uint32_t fb = (bits >> 9) | 0x3f800000u;
    return __uint_as_float(fb) - 1.0f;
}

// ---------------------------------------------------------------------------
// Problem constants
// ---------------------------------------------------------------------------
#define BATCH 32
#define NHEADS 16
#define SEQ 785
#define SIDE 28
#define NDROP 8                        // max(1, int(16*0.5))
#define ROWS_PER_HEAD (BATCH * SIDE)   // 896

// Kernel A: build rowinfo[NDROP*ROWS_PER_HEAD] bytes + headmap[16] (int8)
__global__ void __launch_bounds__(256)
mask_build_kernel(uint8_t* __restrict__ rowinfo, int8_t* __restrict__ headmap) {
    const U2 base = {0u, 42u};              // jax.random.key(42) data = [0, 42]
    int t = blockIdx.x * blockDim.x + threadIdx.x;

    if (t == 0) {
        // k_perm = split(base,2)[0]
        U2 k_perm = blk(base, 0);
        // permutation(k_perm, 16): 1 shuffle round
        // key, subkey = split(k_perm); sort_keys = random_bits(subkey,32,(16,))
        U2 subkey = blk(k_perm, 1);
        uint32_t sk[NHEADS];
        #pragma unroll
        for (int i = 0; i < NHEADS; ++i) sk[i] = rb32(subkey, (uint32_t)i);
        // stable argsort rank; head_idx[:8] = heads with ranks 0..7
        for (int h = 0; h < NHEADS; ++h) {
            int rank = 0;
            for (int i = 0; i < NHEADS; ++i)
                if (sk[i] < sk[h] || (sk[i] == sk[h] && i < h)) ++rank;
            headmap[h] = (rank < NDROP) ? (int8_t)rank : (int8_t)(-1);
        }
    }

    if (t >= NDROP * ROWS_PER_HEAD) return;
    uint32_t j  = (uint32_t)t / ROWS_PER_HEAD;   // drop-head slot 0..7
    uint32_t br = (uint32_t)t % ROWS_PER_HEAD;   // b*28 + r

    U2 k_masks = blk(base, 1);                   // split(base,2)[1]
    U2 hk      = blk(k_masks, j);                // split(k_masks,8)[j]

    // k_row, k_start, k_drop = split(hk, 3)
    U2 k_row   = blk(hk, 0);
    U2 k_start = blk(hk, 1);
    U2 k_drop  = blk(hk, 2);

    // row_sel = uniform(k_row, (32,28)) < 0.1
    uint32_t row_sel = (u01(rb32(k_row, br)) < 0.1f) ? 1u : 0u;

    // start = randint(k_start, (32,28), 0, 27):
    //   higher_key, lower_key = split(k_start); multiplier = (2^16%27)^2%27 = 22
    U2 kh = blk(k_start, 0);
    U2 kl = blk(k_start, 1);
    uint32_t hi = rb32(kh, br);
    uint32_t lo = rb32(kl, br);
    const uint32_t span = 27u;
    uint32_t start = ((hi % span) * 22u + (lo % span)) % span;   // 0..26

    // drop = uniform(k_drop, (32,28,2)) < 0.8 ; flat idx = 2*br + band
    uint32_t drop0 = (u01(rb32(k_drop, 2u * br))      < 0.8f) ? 1u : 0u;
    uint32_t drop1 = (u01(rb32(k_drop, 2u * br + 1u)) < 0.8f) ? 1u : 0u;

    rowinfo[t] = (uint8_t)(row_sel | (drop0 << 1) | (drop1 << 2) | (start << 3));
}

// Kernel B: out = v * mask, float4 streaming
__global__ void __launch_bounds__(256)
apply_mask_kernel(const float4* __restrict__ v, float4* __restrict__ out,
                  const uint8_t* __restrict__ rowinfo,
                  const int8_t* __restrict__ headmap, int nvec) {
    int stride = gridDim.x * blockDim.x;
    for (int i = blockIdx.x * blockDim.x + threadIdx.x; i < nvec; i += stride) {
        float4 val = v[i];
        uint32_t row = (uint32_t)i >> 4;          // 16 float4 per (b,h,s) row
        uint32_t s  = row % SEQ;
        uint32_t bh = row / SEQ;
        uint32_t h  = bh & (NHEADS - 1);
        uint32_t b  = bh >> 4;
        float m = 1.0f;
        int j = headmap[h];
        if (j >= 0 && s >= 1) {                   // s==0 is the special token
            uint32_t pos = s - 1;
            uint32_t r = pos / SIDE;
            uint32_t c = pos - r * SIDE;
            uint32_t info = rowinfo[((uint32_t)j * BATCH + b) * SIDE + r];
            int start = (int)(info >> 3);
            int off = (int)c - start;
            if ((info & 1u) && off >= 0 && off < 2) {
                if ((info >> (1 + off)) & 1u) m = 0.0f;
            }
        }
        val.x *= m; val.y *= m; val.z *= m; val.w *= m;
        out[i] = val;
    }
}

extern "C" void kernel_launch(void* const* d_in, const int* in_sizes, int n_in,
                              void* d_out, int out_size, void* d_ws, size_t ws_size,
                              hipStream_t stream) {
    const float* v = (const float*)d_in[0];
    float* out = (float*)d_out;

    uint8_t* rowinfo = (uint8_t*)d_ws;                        // 7168 bytes
    int8_t*  headmap = (int8_t*)d_ws + NDROP * ROWS_PER_HEAD; // 16 bytes

    mask_build_kernel<<<(NDROP * ROWS_PER_HEAD + 255) / 256, 256, 0, stream>>>(
        rowinfo, headmap);

    int nvec = out_size / 4;   // 25,722,880 / 4 = 6,430,720 float4
    int blocks = 2048;         // grid-stride, ~8 blocks/CU
    apply_mask_kernel<<<blocks, 256, 0, stream>>>(
        (const float4*)v, (float4*)out, rowinfo, headmap, nvec);
}

// Round 4
// 45.027 us; speedup vs baseline: 1.0293x; 1.0293x over previous
//
#include <hip/hip_runtime.h>
#include <stdint.h>

// ---------------------------------------------------------------------------
// JAX threefry2x32, PARTITIONABLE mode (verified bit-exact in R3):
//   split(key,n)[i]              = threefry2x32(key, (0, i))          (both words)
//   random_bits(key,32,shape)[i] = bits1 ^ bits2 of that block        (XOR-fold)
// ---------------------------------------------------------------------------

struct U2 { uint32_t x, y; };

__device__ __forceinline__ uint32_t rotl32(uint32_t v, int r) {
    return (v << r) | (v >> (32 - r));
}

__device__ U2 threefry2x32(uint32_t k0, uint32_t k1, uint32_t c0, uint32_t c1) {
    uint32_t ks2 = k0 ^ k1 ^ 0x1BD11BDAu;
    uint32_t x0 = c0 + k0;
    uint32_t x1 = c1 + k1;
#define TF_RND(r) { x0 += x1; x1 = rotl32(x1, r); x1 ^= x0; }
    TF_RND(13) TF_RND(15) TF_RND(26) TF_RND(6)
    x0 += k1;  x1 += ks2 + 1u;
    TF_RND(17) TF_RND(29) TF_RND(16) TF_RND(24)
    x0 += ks2; x1 += k0 + 2u;
    TF_RND(13) TF_RND(15) TF_RND(26) TF_RND(6)
    x0 += k0;  x1 += k1 + 3u;
    TF_RND(17) TF_RND(29) TF_RND(16) TF_RND(24)
    x0 += k1;  x1 += ks2 + 4u;
    TF_RND(13) TF_RND(15) TF_RND(26) TF_RND(6)
    x0 += ks2; x1 += k0 + 5u;
#undef TF_RND
    U2 r; r.x = x0; r.y = x1; return r;
}

__device__ __forceinline__ U2 blk(U2 key, uint32_t i) {
    return threefry2x32(key.x, key.y, 0u, i);
}
__device__ __forceinline__ uint32_t rb32(U2 key, uint32_t i) {
    U2 b = blk(key, i);
    return b.x ^ b.y;
}
__device__ __forceinline__ float u01(uint32_t bits) {
    uint32_t fb = (bits >> 9) | 0x3f800000u;
    return __uint_as_float(fb) - 1.0f;
}

// ---------------------------------------------------------------------------
#define BATCH 32
#define NHEADS 16
#define SEQ 785
#define SIDE 28
#define NDROP 8                         // max(1, int(16*0.5))
#define ROWS_PER_HEAD (BATCH * SIDE)    // 896
#define TOTAL_ROWS (NDROP * ROWS_PER_HEAD)  // 7168

// Kernel 1: pure streaming copy — m13 pattern (6.29 TB/s), no mask logic.
__global__ void __launch_bounds__(256)
copy_kernel(const float4* __restrict__ v, float4* __restrict__ out, int nvec) {
    int stride = gridDim.x * blockDim.x;
    for (int i = blockIdx.x * blockDim.x + threadIdx.x; i < nvec; i += stride) {
        out[i] = v[i];
    }
}

// Kernel 2: fused RNG + scatter-zero. One thread per (drop-head j, b, r) row;
// only ~16% of threads (row_sel & any-drop) write, 2x64 floats max each.
__global__ void __launch_bounds__(256)
zero_dropped_kernel(float* __restrict__ out) {
    __shared__ uint32_t lds_sk[NHEADS];
    __shared__ int lds_hidx[NDROP];

    const U2 base = {0u, 42u};              // jax.random.key(42) data = [0, 42]

    // head permutation (per block, in LDS): permutation(k_perm, 16), 1 round
    if (threadIdx.x < NHEADS) {
        U2 k_perm  = blk(base, 0);          // split(base,2)[0]
        U2 subkey  = blk(k_perm, 1);        // key,subkey = split(k_perm)
        lds_sk[threadIdx.x] = rb32(subkey, threadIdx.x);
    }
    __syncthreads();
    if (threadIdx.x < NHEADS) {
        uint32_t mysk = lds_sk[threadIdx.x];
        int rank = 0;
        for (int i = 0; i < NHEADS; ++i)
            if (lds_sk[i] < mysk || (lds_sk[i] == mysk && i < (int)threadIdx.x)) ++rank;
        if (rank < NDROP) lds_hidx[rank] = (int)threadIdx.x;  // head_idx[rank]
    }
    __syncthreads();

    int t = blockIdx.x * blockDim.x + threadIdx.x;
    if (t >= TOTAL_ROWS) return;
    uint32_t j  = (uint32_t)t / ROWS_PER_HEAD;   // drop-head slot 0..7
    uint32_t br = (uint32_t)t % ROWS_PER_HEAD;   // b*28 + r

    U2 k_masks = blk(base, 1);                   // split(base,2)[1]
    U2 hk      = blk(k_masks, j);                // split(k_masks,8)[j]

    // row_sel = uniform(k_row, (32,28)) < 0.1
    U2 k_row = blk(hk, 0);
    if (!(u01(rb32(k_row, br)) < 0.1f)) return;

    // start = randint(k_start, (32,28), 0, 27); multiplier = (2^16%27)^2%27 = 22
    U2 k_start = blk(hk, 1);
    U2 k_drop  = blk(hk, 2);
    U2 kh = blk(k_start, 0);
    U2 kl = blk(k_start, 1);
    uint32_t hi = rb32(kh, br);
    uint32_t lo = rb32(kl, br);
    uint32_t start = ((hi % 27u) * 22u + (lo % 27u)) % 27u;   // 0..26

    // drop = uniform(k_drop, (32,28,2)) < 0.8
    uint32_t drop0 = (u01(rb32(k_drop, 2u * br))      < 0.8f) ? 1u : 0u;
    uint32_t drop1 = (u01(rb32(k_drop, 2u * br + 1u)) < 0.8f) ? 1u : 0u;
    if (!(drop0 | drop1)) return;

    uint32_t b = br / SIDE;
    uint32_t r = br % SIDE;
    uint32_t h = (uint32_t)lds_hidx[j];
    // token s = 1 + r*28 + col, col = start (+1); each token row = 64 floats
    size_t rowbase = (((size_t)b * NHEADS + h) * SEQ + 1u + r * SIDE + start) * 64u;

    const float4 z = {0.f, 0.f, 0.f, 0.f};
    if (drop0) {
        float4* p = (float4*)(out + rowbase);
        #pragma unroll
        for (int q = 0; q < 16; ++q) p[q] = z;
    }
    if (drop1) {
        float4* p = (float4*)(out + rowbase + 64u);   // col start+1
        #pragma unroll
        for (int q = 0; q < 16; ++q) p[q] = z;
    }
}

extern "C" void kernel_launch(void* const* d_in, const int* in_sizes, int n_in,
                              void* d_out, int out_size, void* d_ws, size_t ws_size,
                              hipStream_t stream) {
    const float* v = (const float*)d_in[0];
    float* out = (float*)d_out;

    int nvec = out_size / 4;   // 6,430,720 float4
    copy_kernel<<<2048, 256, 0, stream>>>(
        (const float4*)v, (float4*)out, nvec);

    zero_dropped_kernel<<<(TOTAL_ROWS + 255) / 256, 256, 0, stream>>>(out);
}

// Round 5
// 43.436 us; speedup vs baseline: 1.0670x; 1.0366x over previous
//
#include <hip/hip_runtime.h>
#include <stdint.h>

// ---------------------------------------------------------------------------
// JAX threefry2x32, PARTITIONABLE mode (verified bit-exact in R3):
//   split(key,n)[i]              = threefry2x32(key, (0, i))          (both words)
//   random_bits(key,32,shape)[i] = bits1 ^ bits2 of that block        (XOR-fold)
// ---------------------------------------------------------------------------

struct U2 { uint32_t x, y; };

__device__ __forceinline__ uint32_t rotl32(uint32_t v, int r) {
    return (v << r) | (v >> (32 - r));
}

__device__ U2 threefry2x32(uint32_t k0, uint32_t k1, uint32_t c0, uint32_t c1) {
    uint32_t ks2 = k0 ^ k1 ^ 0x1BD11BDAu;
    uint32_t x0 = c0 + k0;
    uint32_t x1 = c1 + k1;
#define TF_RND(r) { x0 += x1; x1 = rotl32(x1, r); x1 ^= x0; }
    TF_RND(13) TF_RND(15) TF_RND(26) TF_RND(6)
    x0 += k1;  x1 += ks2 + 1u;
    TF_RND(17) TF_RND(29) TF_RND(16) TF_RND(24)
    x0 += ks2; x1 += k0 + 2u;
    TF_RND(13) TF_RND(15) TF_RND(26) TF_RND(6)
    x0 += k0;  x1 += k1 + 3u;
    TF_RND(17) TF_RND(29) TF_RND(16) TF_RND(24)
    x0 += k1;  x1 += ks2 + 4u;
    TF_RND(13) TF_RND(15) TF_RND(26) TF_RND(6)
    x0 += ks2; x1 += k0 + 5u;
#undef TF_RND
    U2 r; r.x = x0; r.y = x1; return r;
}

__device__ __forceinline__ U2 blk(U2 key, uint32_t i) {
    return threefry2x32(key.x, key.y, 0u, i);
}
__device__ __forceinline__ uint32_t rb32(U2 key, uint32_t i) {
    U2 b = blk(key, i);
    return b.x ^ b.y;
}
__device__ __forceinline__ float u01(uint32_t bits) {
    uint32_t fb = (bits >> 9) | 0x3f800000u;
    return __uint_as_float(fb) - 1.0f;
}

// ---------------------------------------------------------------------------
#define BATCH 32
#define NHEADS 16
#define SEQ 785
#define SIDE 28
#define NDROP 8                         // max(1, int(16*0.5))
#define ROWS_PER_HEAD (BATCH * SIDE)    // 896
#define TOTAL_ROWS (NDROP * ROWS_PER_HEAD)  // 7168

#define VPT 8          // float4 per thread
#define TPB 256        // threads per block
// block covers TPB*VPT = 2048 float4 = 32 KB, fully contiguous & coalesced

// Kernel 1: streaming copy with 8 independent loads in flight per thread.
__global__ void __launch_bounds__(TPB)
copy_kernel(const float4* __restrict__ v, float4* __restrict__ out, int nvec) {
    int base = blockIdx.x * (TPB * VPT) + threadIdx.x;
    if (base + (VPT - 1) * TPB < nvec) {
        float4 r[VPT];
        #pragma unroll
        for (int k = 0; k < VPT; ++k) r[k] = v[base + k * TPB];
        #pragma unroll
        for (int k = 0; k < VPT; ++k) out[base + k * TPB] = r[k];
    } else {
        #pragma unroll
        for (int k = 0; k < VPT; ++k) {
            int i = base + k * TPB;
            if (i < nvec) out[i] = v[i];
        }
    }
}

// Kernel 2: fused RNG + scatter-zero. One thread per (drop-head j, b, r) row;
// only ~8% of threads (row_sel & any-drop) write, 2x64 floats max each.
__global__ void __launch_bounds__(256)
zero_dropped_kernel(float* __restrict__ out) {
    __shared__ uint32_t lds_sk[NHEADS];
    __shared__ int lds_hidx[NDROP];

    const U2 base = {0u, 42u};              // jax.random.key(42) data = [0, 42]

    // head permutation (per block, in LDS): permutation(k_perm, 16), 1 round
    if (threadIdx.x < NHEADS) {
        U2 k_perm  = blk(base, 0);          // split(base,2)[0]
        U2 subkey  = blk(k_perm, 1);        // key,subkey = split(k_perm)
        lds_sk[threadIdx.x] = rb32(subkey, threadIdx.x);
    }
    __syncthreads();
    if (threadIdx.x < NHEADS) {
        uint32_t mysk = lds_sk[threadIdx.x];
        int rank = 0;
        for (int i = 0; i < NHEADS; ++i)
            if (lds_sk[i] < mysk || (lds_sk[i] == mysk && i < (int)threadIdx.x)) ++rank;
        if (rank < NDROP) lds_hidx[rank] = (int)threadIdx.x;  // head_idx[rank]
    }
    __syncthreads();

    int t = blockIdx.x * blockDim.x + threadIdx.x;
    if (t >= TOTAL_ROWS) return;
    uint32_t j  = (uint32_t)t / ROWS_PER_HEAD;   // drop-head slot 0..7
    uint32_t br = (uint32_t)t % ROWS_PER_HEAD;   // b*28 + r

    U2 k_masks = blk(base, 1);                   // split(base,2)[1]
    U2 hk      = blk(k_masks, j);                // split(k_masks,8)[j]

    // row_sel = uniform(k_row, (32,28)) < 0.1
    U2 k_row = blk(hk, 0);
    if (!(u01(rb32(k_row, br)) < 0.1f)) return;

    // start = randint(k_start, (32,28), 0, 27); multiplier = (2^16%27)^2%27 = 22
    U2 k_start = blk(hk, 1);
    U2 k_drop  = blk(hk, 2);
    U2 kh = blk(k_start, 0);
    U2 kl = blk(k_start, 1);
    uint32_t hi = rb32(kh, br);
    uint32_t lo = rb32(kl, br);
    uint32_t start = ((hi % 27u) * 22u + (lo % 27u)) % 27u;   // 0..26

    // drop = uniform(k_drop, (32,28,2)) < 0.8
    uint32_t drop0 = (u01(rb32(k_drop, 2u * br))      < 0.8f) ? 1u : 0u;
    uint32_t drop1 = (u01(rb32(k_drop, 2u * br + 1u)) < 0.8f) ? 1u : 0u;
    if (!(drop0 | drop1)) return;

    uint32_t b = br / SIDE;
    uint32_t r = br % SIDE;
    uint32_t h = (uint32_t)lds_hidx[j];
    // token s = 1 + r*28 + col, col = start (+1); each token row = 64 floats
    size_t rowbase = (((size_t)b * NHEADS + h) * SEQ + 1u + r * SIDE + start) * 64u;

    const float4 z = {0.f, 0.f, 0.f, 0.f};
    if (drop0) {
        float4* p = (float4*)(out + rowbase);
        #pragma unroll
        for (int q = 0; q < 16; ++q) p[q] = z;
    }
    if (drop1) {
        float4* p = (float4*)(out + rowbase + 64u);   // col start+1
        #pragma unroll
        for (int q = 0; q < 16; ++q) p[q] = z;
    }
}

extern "C" void kernel_launch(void* const* d_in, const int* in_sizes, int n_in,
                              void* d_out, int out_size, void* d_ws, size_t ws_size,
                              hipStream_t stream) {
    const float* v = (const float*)d_in[0];
    float* out = (float*)d_out;

    int nvec = out_size / 4;                       // 6,430,720 float4
    int blocks = (nvec + TPB * VPT - 1) / (TPB * VPT);  // 3140 exact
    copy_kernel<<<blocks, TPB, 0, stream>>>(
        (const float4*)v, (float4*)out, nvec);

    zero_dropped_kernel<<<(TOTAL_ROWS + 255) / 256, 256, 0, stream>>>(out);
}

// Round 7
// 42.954 us; speedup vs baseline: 1.0790x; 1.0112x over previous
//
#include <hip/hip_runtime.h>
#include <stdint.h>

// ---------------------------------------------------------------------------
// JAX threefry2x32, PARTITIONABLE mode (verified bit-exact in R3):
//   split(key,n)[i]              = threefry2x32(key, (0, i))          (both words)
//   random_bits(key,32,shape)[i] = bits1 ^ bits2 of that block        (XOR-fold)
// ---------------------------------------------------------------------------

struct U2 { uint32_t x, y; };

typedef float f32x4 __attribute__((ext_vector_type(4)));  // native vec: OK for
                                                          // __builtin_nontemporal_*

__device__ __forceinline__ uint32_t rotl32(uint32_t v, int r) {
    return (v << r) | (v >> (32 - r));
}

__device__ U2 threefry2x32(uint32_t k0, uint32_t k1, uint32_t c0, uint32_t c1) {
    uint32_t ks2 = k0 ^ k1 ^ 0x1BD11BDAu;
    uint32_t x0 = c0 + k0;
    uint32_t x1 = c1 + k1;
#define TF_RND(r) { x0 += x1; x1 = rotl32(x1, r); x1 ^= x0; }
    TF_RND(13) TF_RND(15) TF_RND(26) TF_RND(6)
    x0 += k1;  x1 += ks2 + 1u;
    TF_RND(17) TF_RND(29) TF_RND(16) TF_RND(24)
    x0 += ks2; x1 += k0 + 2u;
    TF_RND(13) TF_RND(15) TF_RND(26) TF_RND(6)
    x0 += k0;  x1 += k1 + 3u;
    TF_RND(17) TF_RND(29) TF_RND(16) TF_RND(24)
    x0 += k1;  x1 += ks2 + 4u;
    TF_RND(13) TF_RND(15) TF_RND(26) TF_RND(6)
    x0 += ks2; x1 += k0 + 5u;
#undef TF_RND
    U2 r; r.x = x0; r.y = x1; return r;
}

__device__ __forceinline__ U2 blk(U2 key, uint32_t i) {
    return threefry2x32(key.x, key.y, 0u, i);
}
__device__ __forceinline__ uint32_t rb32(U2 key, uint32_t i) {
    U2 b = blk(key, i);
    return b.x ^ b.y;
}
__device__ __forceinline__ float u01(uint32_t bits) {
    uint32_t fb = (bits >> 9) | 0x3f800000u;
    return __uint_as_float(fb) - 1.0f;
}

// ---------------------------------------------------------------------------
#define BATCH 32
#define NHEADS 16
#define SEQ 785
#define SIDE 28
#define NDROP 8                         // max(1, int(16*0.5))
#define ROWS_PER_HEAD (BATCH * SIDE)    // 896
#define TOTAL_ROWS (NDROP * ROWS_PER_HEAD)  // 7168

#define VPT 8          // float4 per thread
#define TPB 256        // threads per block
// nvec = 6,430,720 = 3140 * (256*8) exactly -> fast path always, no tail.

// Kernel 1: streaming copy, 8 loads in flight, NONTEMPORAL stores (no-allocate:
// don't evict the L3-resident input with write allocation).
__global__ void __launch_bounds__(TPB)
copy_kernel(const f32x4* __restrict__ v, f32x4* __restrict__ out, int nvec) {
    int base = blockIdx.x * (TPB * VPT) + threadIdx.x;
    if (base + (VPT - 1) * TPB < nvec) {
        f32x4 r[VPT];
        #pragma unroll
        for (int k = 0; k < VPT; ++k) r[k] = v[base + k * TPB];
        #pragma unroll
        for (int k = 0; k < VPT; ++k)
            __builtin_nontemporal_store(r[k], &out[base + k * TPB]);
    } else {
        #pragma unroll
        for (int k = 0; k < VPT; ++k) {
            int i = base + k * TPB;
            if (i < nvec) __builtin_nontemporal_store(v[i], &out[i]);
        }
    }
}

// Kernel 2: fused RNG + scatter-zero. One thread per (drop-head j, b, r) row;
// only ~8% of threads (row_sel & any-drop) write, 2x64 floats max each.
__global__ void __launch_bounds__(256)
zero_dropped_kernel(float* __restrict__ out) {
    __shared__ uint32_t lds_sk[NHEADS];
    __shared__ int lds_hidx[NDROP];

    const U2 base = {0u, 42u};              // jax.random.key(42) data = [0, 42]

    // head permutation (per block, in LDS): permutation(k_perm, 16), 1 round
    if (threadIdx.x < NHEADS) {
        U2 k_perm  = blk(base, 0);          // split(base,2)[0]
        U2 subkey  = blk(k_perm, 1);        // key,subkey = split(k_perm)
        lds_sk[threadIdx.x] = rb32(subkey, threadIdx.x);
    }
    __syncthreads();
    if (threadIdx.x < NHEADS) {
        uint32_t mysk = lds_sk[threadIdx.x];
        int rank = 0;
        for (int i = 0; i < NHEADS; ++i)
            if (lds_sk[i] < mysk || (lds_sk[i] == mysk && i < (int)threadIdx.x)) ++rank;
        if (rank < NDROP) lds_hidx[rank] = (int)threadIdx.x;  // head_idx[rank]
    }
    __syncthreads();

    int t = blockIdx.x * blockDim.x + threadIdx.x;
    if (t >= TOTAL_ROWS) return;
    uint32_t j  = (uint32_t)t / ROWS_PER_HEAD;   // drop-head slot 0..7
    uint32_t br = (uint32_t)t % ROWS_PER_HEAD;   // b*28 + r

    U2 k_masks = blk(base, 1);                   // split(base,2)[1]
    U2 hk      = blk(k_masks, j);                // split(k_masks,8)[j]

    // row_sel = uniform(k_row, (32,28)) < 0.1
    U2 k_row = blk(hk, 0);
    if (!(u01(rb32(k_row, br)) < 0.1f)) return;

    // start = randint(k_start, (32,28), 0, 27); multiplier = (2^16%27)^2%27 = 22
    U2 k_start = blk(hk, 1);
    U2 k_drop  = blk(hk, 2);
    U2 kh = blk(k_start, 0);
    U2 kl = blk(k_start, 1);
    uint32_t hi = rb32(kh, br);
    uint32_t lo = rb32(kl, br);
    uint32_t start = ((hi % 27u) * 22u + (lo % 27u)) % 27u;   // 0..26

    // drop = uniform(k_drop, (32,28,2)) < 0.8
    uint32_t drop0 = (u01(rb32(k_drop, 2u * br))      < 0.8f) ? 1u : 0u;
    uint32_t drop1 = (u01(rb32(k_drop, 2u * br + 1u)) < 0.8f) ? 1u : 0u;
    if (!(drop0 | drop1)) return;

    uint32_t b = br / SIDE;
    uint32_t r = br % SIDE;
    uint32_t h = (uint32_t)lds_hidx[j];
    // token s = 1 + r*28 + col, col = start (+1); each token row = 64 floats
    size_t rowbase = (((size_t)b * NHEADS + h) * SEQ + 1u + r * SIDE + start) * 64u;

    const f32x4 z = {0.f, 0.f, 0.f, 0.f};
    if (drop0) {
        f32x4* p = (f32x4*)(out + rowbase);
        #pragma unroll
        for (int q = 0; q < 16; ++q) p[q] = z;
    }
    if (drop1) {
        f32x4* p = (f32x4*)(out + rowbase + 64u);   // col start+1
        #pragma unroll
        for (int q = 0; q < 16; ++q) p[q] = z;
    }
}

extern "C" void kernel_launch(void* const* d_in, const int* in_sizes, int n_in,
                              void* d_out, int out_size, void* d_ws, size_t ws_size,
                              hipStream_t stream) {
    const float* v = (const float*)d_in[0];
    float* out = (float*)d_out;

    int nvec = out_size / 4;                       // 6,430,720 float4
    int blocks = (nvec + TPB * VPT - 1) / (TPB * VPT);  // 3140 exact
    copy_kernel<<<blocks, TPB, 0, stream>>>(
        (const f32x4*)v, (f32x4*)out, nvec);

    zero_dropped_kernel<<<(TOTAL_ROWS + 255) / 256, 256, 0, stream>>>(out);
}

// Round 8
// 36.556 us; speedup vs baseline: 1.2678x; 1.1750x over previous
//
#include <hip/hip_runtime.h>
#include <stdint.h>

// ---------------------------------------------------------------------------
// JAX threefry2x32, PARTITIONABLE mode (verified bit-exact in R3):
//   split(key,n)[i]              = threefry2x32(key, (0, i))          (both words)
//   random_bits(key,32,shape)[i] = bits1 ^ bits2 of that block        (XOR-fold)
// ---------------------------------------------------------------------------

struct U2 { uint32_t x, y; };

typedef float f32x4 __attribute__((ext_vector_type(4)));

__device__ __forceinline__ uint32_t rotl32(uint32_t v, int r) {
    return (v << r) | (v >> (32 - r));
}

__device__ U2 threefry2x32(uint32_t k0, uint32_t k1, uint32_t c0, uint32_t c1) {
    uint32_t ks2 = k0 ^ k1 ^ 0x1BD11BDAu;
    uint32_t x0 = c0 + k0;
    uint32_t x1 = c1 + k1;
#define TF_RND(r) { x0 += x1; x1 = rotl32(x1, r); x1 ^= x0; }
    TF_RND(13) TF_RND(15) TF_RND(26) TF_RND(6)
    x0 += k1;  x1 += ks2 + 1u;
    TF_RND(17) TF_RND(29) TF_RND(16) TF_RND(24)
    x0 += ks2; x1 += k0 + 2u;
    TF_RND(13) TF_RND(15) TF_RND(26) TF_RND(6)
    x0 += k0;  x1 += k1 + 3u;
    TF_RND(17) TF_RND(29) TF_RND(16) TF_RND(24)
    x0 += k1;  x1 += ks2 + 4u;
    TF_RND(13) TF_RND(15) TF_RND(26) TF_RND(6)
    x0 += ks2; x1 += k0 + 5u;
#undef TF_RND
    U2 r; r.x = x0; r.y = x1; return r;
}

__device__ __forceinline__ U2 blk(U2 key, uint32_t i) {
    return threefry2x32(key.x, key.y, 0u, i);
}
__device__ __forceinline__ uint32_t rb32(U2 key, uint32_t i) {
    U2 b = blk(key, i);
    return b.x ^ b.y;
}
__device__ __forceinline__ float u01(uint32_t bits) {
    uint32_t fb = (bits >> 9) | 0x3f800000u;
    return __uint_as_float(fb) - 1.0f;
}

// ---------------------------------------------------------------------------
#define BATCH 32
#define NHEADS 16
#define SEQ 785
#define SIDE 28
#define NDROP 8                          // max(1, int(16*0.5))

#define VPT 8                            // float4 per thread
#define TPB 256                          // threads per block
#define TOK_PER_BLK ((TPB * VPT) / 16)   // 128 tokens (64 floats each)
// nvec = 6,430,720 = 3140 * 2048 exactly -> every block full, no tail.

// Single fused kernel: copy + on-the-fly mask recompute + NT store.
// Loads issued first; RNG (LDS-staged, per-block) hides under HBM latency.
__global__ void __launch_bounds__(TPB)
fused_dropout_kernel(const f32x4* __restrict__ v, f32x4* __restrict__ out) {
    __shared__ uint32_t lds_sk[NHEADS];
    __shared__ int      lds_hm[NHEADS];      // head -> drop slot j, or -1
    __shared__ float    lds_m[TOK_PER_BLK];  // per-token multiplier

    const U2 base = {0u, 42u};               // jax.random.key(42) data = [0,42]

    const int base4 = blockIdx.x * (TPB * VPT) + threadIdx.x;

    // 1) issue all 8 independent loads up front (waitcnt lands after barrier)
    f32x4 r[VPT];
    #pragma unroll
    for (int k = 0; k < VPT; ++k) r[k] = v[base4 + k * TPB];

    // 2) head permutation: permutation(k_perm, 16), 1 shuffle round
    if (threadIdx.x < NHEADS) {
        U2 k_perm = blk(base, 0);            // split(base,2)[0]
        U2 subkey = blk(k_perm, 1);          // key,subkey = split(k_perm)
        lds_sk[threadIdx.x] = rb32(subkey, threadIdx.x);
    }
    __syncthreads();
    if (threadIdx.x < NHEADS) {
        uint32_t mysk = lds_sk[threadIdx.x];
        int rank = 0;
        for (int i = 0; i < NHEADS; ++i)
            if (lds_sk[i] < mysk || (lds_sk[i] == mysk && i < (int)threadIdx.x)) ++rank;
        lds_hm[threadIdx.x] = (rank < NDROP) ? rank : -1;   // head_idx slot
    }
    __syncthreads();

    // 3) per-token mask (threads 0..127), short-circuiting RNG chain
    if (threadIdx.x < TOK_PER_BLK) {
        int tok = blockIdx.x * TOK_PER_BLK + threadIdx.x;
        uint32_t s  = (uint32_t)tok % SEQ;
        uint32_t bh = (uint32_t)tok / SEQ;
        uint32_t h  = bh & (NHEADS - 1);
        uint32_t b  = bh >> 4;
        float m = 1.0f;
        int j = lds_hm[h];
        if (j >= 0 && s >= 1) {              // s==0 is the special token
            uint32_t pos = s - 1;
            uint32_t rr = pos / SIDE;
            uint32_t c  = pos - rr * SIDE;
            uint32_t br = b * SIDE + rr;
            U2 k_masks = blk(base, 1);       // split(base,2)[1]
            U2 hk      = blk(k_masks, (uint32_t)j);
            U2 k_row   = blk(hk, 0);
            if (u01(rb32(k_row, br)) < 0.1f) {               // row selected
                U2 k_start = blk(hk, 1);
                U2 kh = blk(k_start, 0);
                U2 kl = blk(k_start, 1);
                uint32_t hi = rb32(kh, br);
                uint32_t lo = rb32(kl, br);
                uint32_t start = ((hi % 27u) * 22u + (lo % 27u)) % 27u;
                int off = (int)c - (int)start;
                if (off >= 0 && off < 2) {                   // inside band
                    U2 k_drop = blk(hk, 2);
                    if (u01(rb32(k_drop, 2u * br + (uint32_t)off)) < 0.8f)
                        m = 0.0f;
                }
            }
        }
        lds_m[threadIdx.x] = m;
    }
    __syncthreads();

    // 4) multiply + nontemporal store
    #pragma unroll
    for (int k = 0; k < VPT; ++k) {
        int i4 = threadIdx.x + k * TPB;      // local float4 index in block span
        float m = lds_m[i4 >> 4];
        r[k] *= m;
        __builtin_nontemporal_store(r[k], &out[base4 + k * TPB]);
    }
}

extern "C" void kernel_launch(void* const* d_in, const int* in_sizes, int n_in,
                              void* d_out, int out_size, void* d_ws, size_t ws_size,
                              hipStream_t stream) {
    const float* v = (const float*)d_in[0];
    float* out = (float*)d_out;

    int nvec = out_size / 4;                      // 6,430,720 float4
    int blocks = nvec / (TPB * VPT);              // 3140, exact
    fused_dropout_kernel<<<blocks, TPB, 0, stream>>>(
        (const f32x4*)v, (f32x4*)out);
}